// Round 18
// baseline (102.911 us; speedup 1.0000x reference)
//
#include <hip/hip_runtime.h>
#include <hip/hip_bf16.h>
#include <stdint.h>

#define B_   512
#define C_   440
#define CR_  52
#define HW_  49
#define KP_  448          // padded K (=C), 7*64
#define OP_  512          // padded O: 4 o-tiles of 128
#define M_   25088        // B_*HW_ (= 196*128 exactly)
#define CCH_ 64           // c-chunk per scatter block
#define TSS_ 72           // scatter LDS row stride (shorts)
#define NKT_ 14           // K-steps (448/32), BK=32

typedef __attribute__((ext_vector_type(8))) short bf8;
typedef __attribute__((ext_vector_type(4))) float f4;

__device__ __forceinline__ unsigned short f2bf(float f) {
  union { float f; unsigned u; } v; v.f = f;
  unsigned r = v.u + 0x7FFFu + ((v.u >> 16) & 1u);
  return (unsigned short)(r >> 16);
}
__device__ __forceinline__ float bf2f(unsigned short u) {
  union { unsigned u; float f; } v; v.u = ((unsigned)u) << 16; return v.f;
}

// ---- K1: merged prep+gate. Blocks [0,896): w3 fp32->bf16 padded (+gstats=0).
//      Blocks [896,1408): per-b gate MLP -> gate[b][c]. Disjoint outputs. ----
__global__ __launch_bounds__(256) void k_prep_gate(
    const float* __restrict__ w3, unsigned short* __restrict__ w3bf,
    float* __restrict__ gstats,
    const float* __restrict__ x178,
    const float* __restrict__ w1, const float* __restrict__ b1,
    const float* __restrict__ w2, const float* __restrict__ b2,
    float* __restrict__ gate) {
  __shared__ __align__(16) float s_s[C_];
  __shared__ __align__(16) float s_h[CR_ + 12];   // padded to 64 floats
  int tid = threadIdx.x;

  if (blockIdx.x < 896) {                          // ---- prep branch ----
    int idx = blockIdx.x * 256 + tid;              // covers 512*448 exactly
    if (blockIdx.x == 0) {
      #pragma unroll
      for (int i = 0; i < 4; ++i) gstats[tid + i * 256] = 0.f;  // 2*OP_ floats
    }
    int o = idx / KP_, c = idx - o * KP_;
    float v = (c < C_ && o < C_) ? w3[o * C_ + c] : 0.f;
    w3bf[idx] = f2bf(v);
    return;
  }
  // ---- gate branch ----
  int b = blockIdx.x - 896;

  if (tid < C_ / 4) ((f4*)s_s)[tid] = ((const f4*)(x178 + (size_t)b * C_))[tid];
  if (tid >= 240 && tid < 240 + 16) ((f4*)s_h)[tid - 240] = f4{0.f, 0.f, 0.f, 0.f};
  __syncthreads();

  int r = tid >> 2, q = tid & 3;     // 64 rows x 4 threads
  if (r < CR_) {
    const f4* wr = (const f4*)(w1 + (size_t)r * C_);   // 110 f4 per row
    const f4* ss = (const f4*)s_s;
    f4 acc = {0.f, 0.f, 0.f, 0.f};
    #pragma unroll
    for (int j0 = 0; j0 < 28; ++j0) {
      int j = q + j0 * 4;
      if (j < C_ / 4) { f4 w = wr[j], x = ss[j]; acc += w * x; }
    }
    float a = acc[0] + acc[1] + acc[2] + acc[3];
    a += __shfl_xor(a, 1, 64);
    a += __shfl_xor(a, 2, 64);
    if (q == 0) s_h[r] = fmaxf(a + b1[r], 0.f);
  }
  __syncthreads();

  for (int c = tid; c < C_; c += 256) {
    const f4* wc = (const f4*)(w2 + (size_t)c * CR_);  // 13 f4 per row
    const f4* hh = (const f4*)s_h;
    f4 acc = {0.f, 0.f, 0.f, 0.f};
    #pragma unroll
    for (int j = 0; j < 13; ++j) acc += wc[j] * hh[j];
    float a = acc[0] + acc[1] + acc[2] + acc[3] + b2[c];
    gate[b * C_ + c] = 1.f / (1.f + __expf(-a));
  }
}

// ------- K2: gating + bf16 + transpose, one block per (c-chunk, b) -------
__global__ __launch_bounds__(256) void k_scatter(
    const float* __restrict__ x177, const float* __restrict__ gate,
    unsigned short* __restrict__ gbf) {
  __shared__ __align__(16) unsigned short s_t[HW_ * TSS_];  // [49][72] bf16
  __shared__ float s_g[CCH_];
  int cc = blockIdx.x, b = blockIdx.y, tid = threadIdx.x;
  int c0 = cc * CCH_;
  int valid_c = (c0 + CCH_ <= C_) ? CCH_ : (C_ - c0);   // 64 or 56

  unsigned* zt = (unsigned*)s_t;
  for (int i = tid; i < HW_ * TSS_ / 2; i += 256) zt[i] = 0u;
  if (tid < CCH_) {
    int c = c0 + tid;
    s_g[tid] = (c < C_) ? gate[b * C_ + c] : 0.f;
  }
  __syncthreads();

  const f4* xp = (const f4*)(x177 + (size_t)b * (C_ * HW_) + (size_t)c0 * HW_);
  int nvec = valid_c * HW_ / 4;   // 784 or 686
  for (int it = 0; it < 4; ++it) {
    int idx = it * 256 + tid;
    if (idx < nvec) {
      f4 v = xp[idx];
      int e = idx * 4;
      #pragma unroll
      for (int j = 0; j < 4; ++j) {
        int ej = e + j;
        int cl = ej / HW_, hw = ej - cl * HW_;
        s_t[hw * TSS_ + cl] = f2bf(v[j] * s_g[cl]);
      }
    }
  }
  __syncthreads();

  unsigned short* gp = gbf + (size_t)b * HW_ * KP_ + c0;
  for (int it = 0; it < 2; ++it) {
    int p = it * 256 + tid;
    if (p < HW_ * (CCH_ / 8)) {
      int hw = p >> 3, cg = p & 7;
      *(bf8*)(gp + hw * KP_ + cg * 8) = *(const bf8*)(s_t + hw * TSS_ + cg * 8);
    }
  }
}

// ---- K3: BOTH operands direct-to-reg from L2/L3 (w3bf 448KB, gbf 22MB).
// Register double-buffer: loads for kt+1 issue before MFMAs of kt.
// NO LDS in main loop, NO barriers, no convoy — waves run free; latency
// hidden by 1-step-ahead loads + 4 waves/SIMD TLP. ----
__global__ __launch_bounds__(256, 4) void k_gemm(const unsigned short* __restrict__ w3bf,
                                                 const unsigned short* __restrict__ gbf,
                                                 unsigned short* __restrict__ ybf,
                                                 float* __restrict__ gstats) {
  __shared__ float part[128 * 4];           // stats epilogue only (2 KB)
  int tid = threadIdx.x, lane = tid & 63, wv = tid >> 6;
  // XCD swizzle: 784 = 8 chunks x 98; g = x*98+j, ot = g%4, mt = g/4
  int bid0 = blockIdx.x;
  int g = (bid0 & 7) * 98 + (bid0 >> 3);
  int ot = g & 3, mt = g >> 2;
  int o0 = ot * 128, m0 = mt * 128;
  int wr = wv >> 1, wc = wv & 1;            // wave: 64o x 64m quadrant
  f4 acc[4][4] = {};
  const char* Ab = (const char*)w3bf;  // row stride 896 B
  const char* Bb = (const char*)gbf;   // row stride 896 B

  int rl = lane & 15, l16q = lane >> 4;
  // per-lane fragment bases (lanes rl, rl+16, rl+32, rl+48 share each 64B line)
  const char* Abase = Ab + (size_t)(o0 + wr * 64 + rl) * 896 + l16q * 16;
  const char* Bbase = Bb + (size_t)(m0 + wc * 64 + rl) * 896 + l16q * 16;

  auto lf = [&](bf8 (&a)[4], bf8 (&b)[4], int kt) {
    int k0b = kt * 64;
    #pragma unroll
    for (int i = 0; i < 4; ++i)
      a[i] = *(const bf8*)(Abase + (size_t)(i * 16) * 896 + k0b);
    #pragma unroll
    for (int j = 0; j < 4; ++j)
      b[j] = *(const bf8*)(Bbase + (size_t)(j * 16) * 896 + k0b);
  };
  auto mm = [&](bf8 (&a)[4], bf8 (&b)[4]) {
    #pragma unroll
    for (int i = 0; i < 4; ++i)
      #pragma unroll
      for (int j = 0; j < 4; ++j)
        acc[i][j] = __builtin_amdgcn_mfma_f32_16x16x32_bf16(a[i], b[j], acc[i][j], 0, 0, 0);
  };

  bf8 aA[4], bA[4], aB[4], bB[4];
  lf(aA, bA, 0);
  #pragma unroll
  for (int kt = 0; kt < NKT_; kt += 2) {    // NKT_=14, even
    if (kt + 1 < NKT_) lf(aB, bB, kt + 1);  // issue next-step loads first
    mm(aA, bA);                             // compiler waits only on (aA,bA)
    if (kt + 2 < NKT_) lf(aA, bA, kt + 2);
    if (kt + 1 < NKT_) mm(aB, bB);
  }

  // D layout: col = lane&15 (m), row = (lane>>4)*4 + reg (o); store bf16
  int col = rl, r4 = l16q * 4;
  #pragma unroll
  for (int i = 0; i < 4; ++i) {
    int ob = o0 + wr * 64 + i * 16 + r4;
    #pragma unroll
    for (int j = 0; j < 4; ++j) {
      int m = m0 + wc * 64 + j * 16 + col;
      #pragma unroll
      for (int r = 0; r < 4; ++r) {
        int o = ob + r;
        if (o < C_) ybf[(size_t)o * M_ + m] = f2bf(acc[i][j][r]);
      }
    }
  }

  // fused stats: per-block sum/sumsq over this block's 128 m-cols
  __syncthreads();
  #pragma unroll
  for (int i = 0; i < 4; ++i) {
    float s[4], q[4];
    #pragma unroll
    for (int r = 0; r < 4; ++r) {
      float ss = 0.f, qq = 0.f;
      #pragma unroll
      for (int j = 0; j < 4; ++j) { float v = acc[i][j][r]; ss += v; qq += v * v; }
      s[r] = ss; q[r] = qq;
    }
    #pragma unroll
    for (int off = 1; off < 16; off <<= 1) {
      #pragma unroll
      for (int r = 0; r < 4; ++r) {
        s[r] += __shfl_xor(s[r], off, 64);
        q[r] += __shfl_xor(q[r], off, 64);
      }
    }
    if (rl == 0) {
      int row = wr * 64 + i * 16 + r4;
      #pragma unroll
      for (int r = 0; r < 4; ++r) {
        part[(row + r) * 4 + wc * 2 + 0] = s[r];
        part[(row + r) * 4 + wc * 2 + 1] = q[r];
      }
    }
  }
  __syncthreads();
  {
    int row = tid >> 1, which = tid & 1;
    float v = part[row * 4 + which] + part[row * 4 + 2 + which];
    int o = o0 + row;
    if (o < C_) atomicAdd(&gstats[o * 2 + which], v);
  }
}

// -------- K4: block-per-b normalize, flat f4 stores (fully coalesced) --------
__global__ __launch_bounds__(256) void k_norm(const unsigned short* __restrict__ ybf,
                                              const float* __restrict__ gstats,
                                              const float* __restrict__ gamma,
                                              const float* __restrict__ beta,
                                              float* __restrict__ out) {
  __shared__ float s_sc[C_], s_sh[C_];
  int b = blockIdx.x, seg = blockIdx.y, tid = threadIdx.x;
  for (int o = tid; o < C_; o += 256) {
    float S = gstats[o * 2 + 0], Q = gstats[o * 2 + 1];
    float mean = S * (1.f / (float)M_);
    float var  = Q * (1.f / (float)M_) - mean * mean;
    float sc = gamma[o] * rsqrtf(var + 1e-5f);
    s_sc[o] = sc;
    s_sh[o] = beta[o] - mean * sc;
  }
  __syncthreads();
  // out region for b: 21560 floats = 5390 f4 (16B-aligned); split in 2 segs
  f4* ob = (f4*)(out + (size_t)b * (C_ * HW_));
  int mb = b * HW_;
  for (int u = seg * 2695 + tid; u < (seg + 1) * 2695; u += 256) {
    int f = u * 4;
    f4 v;
    #pragma unroll
    for (int j = 0; j < 4; ++j) {
      int fj = f + j;
      int o = fj / HW_, hw = fj - o * HW_;
      v[j] = bf2f(ybf[(size_t)o * M_ + mb + hw]) * s_sc[o] + s_sh[o];
    }
    ob[u] = v;
  }
}

extern "C" void kernel_launch(void* const* d_in, const int* in_sizes, int n_in,
                              void* d_out, int out_size, void* d_ws, size_t ws_size,
                              hipStream_t stream) {
  const float* x178 = (const float*)d_in[0];
  const float* x177 = (const float*)d_in[1];
  const float* w1   = (const float*)d_in[2];
  const float* b1   = (const float*)d_in[3];
  const float* w2   = (const float*)d_in[4];
  const float* b2   = (const float*)d_in[5];
  const float* w3   = (const float*)d_in[6];
  const float* gamma= (const float*)d_in[7];
  const float* beta = (const float*)d_in[8];
  float* out = (float*)d_out;

  char* ws = (char*)d_ws;
  unsigned short* w3bf = (unsigned short*)ws;                        // 512*448*2
  unsigned short* gbf  = (unsigned short*)(ws + 458752);             // 25088*448*2
  unsigned short* ybf  = (unsigned short*)(ws + 458752 + 22478848);  // region reserves 44MB
  float* gstats        = (float*)(ws + 458752 + 22478848 + 44154880);
  float* gate          = (float*)ybf;  // consumed by k_scatter before k_gemm writes ybf

  hipLaunchKernelGGL(k_prep_gate, dim3(896 + B_), dim3(256), 0, stream,
                     w3, w3bf, gstats, x178, w1, b1, w2, b2, gate);
  hipLaunchKernelGGL(k_scatter, dim3(KP_ / CCH_, B_), dim3(256), 0, stream,
                     x177, gate, gbf);
  hipLaunchKernelGGL(k_gemm, dim3((M_ / 128) * (OP_ / 128)), dim3(256), 0, stream,
                     w3bf, gbf, ybf, gstats);
  hipLaunchKernelGGL(k_norm, dim3(B_, 2), dim3(256), 0, stream,
                     ybf, gstats, gamma, beta, out);
}

// Round 19
// 74.173 us; speedup vs baseline: 1.3874x; 1.3874x over previous
//
#include <hip/hip_runtime.h>
#include <hip/hip_bf16.h>
#include <stdint.h>

#define B_   512
#define C_   440
#define CR_  52
#define HW_  49
#define KP_  448          // padded K (=C), 7*64
#define OP_  512          // padded O: 4 o-tiles of 128
#define M_   25088        // B_*HW_ (= 392*64 exactly)
#define CCH_ 64           // c-chunk per scatter block
#define TSS_ 72           // scatter LDS row stride (shorts)
#define NKT_ 14           // K-steps (448/32), BK=32

typedef __attribute__((ext_vector_type(8))) short bf8;
typedef __attribute__((ext_vector_type(4))) float f4;

__device__ __forceinline__ unsigned short f2bf(float f) {
  union { float f; unsigned u; } v; v.f = f;
  unsigned r = v.u + 0x7FFFu + ((v.u >> 16) & 1u);
  return (unsigned short)(r >> 16);
}
__device__ __forceinline__ float bf2f(unsigned short u) {
  union { unsigned u; float f; } v; v.u = ((unsigned)u) << 16; return v.f;
}

__device__ __forceinline__ void gld16(const void* g, void* l) {
  __builtin_amdgcn_global_load_lds(
      (const __attribute__((address_space(1))) unsigned int*)g,
      (__attribute__((address_space(3))) unsigned int*)l, 16, 0, 0);
}

// ---- K1: merged prep+gate. Blocks [0,896): w3 fp32->bf16 padded (+gstats=0).
//      Blocks [896,1408): per-b gate MLP -> gate[b][c]. Disjoint outputs. ----
__global__ __launch_bounds__(256) void k_prep_gate(
    const float* __restrict__ w3, unsigned short* __restrict__ w3bf,
    float* __restrict__ gstats,
    const float* __restrict__ x178,
    const float* __restrict__ w1, const float* __restrict__ b1,
    const float* __restrict__ w2, const float* __restrict__ b2,
    float* __restrict__ gate) {
  __shared__ __align__(16) float s_s[C_];
  __shared__ __align__(16) float s_h[CR_ + 12];   // padded to 64 floats
  int tid = threadIdx.x;

  if (blockIdx.x < 896) {                          // ---- prep branch ----
    int idx = blockIdx.x * 256 + tid;              // covers 512*448 exactly
    if (blockIdx.x == 0) {
      #pragma unroll
      for (int i = 0; i < 4; ++i) gstats[tid + i * 256] = 0.f;  // 2*OP_ floats
    }
    int o = idx / KP_, c = idx - o * KP_;
    float v = (c < C_ && o < C_) ? w3[o * C_ + c] : 0.f;
    w3bf[idx] = f2bf(v);
    return;
  }
  // ---- gate branch ----
  int b = blockIdx.x - 896;

  if (tid < C_ / 4) ((f4*)s_s)[tid] = ((const f4*)(x178 + (size_t)b * C_))[tid];
  if (tid >= 240 && tid < 240 + 16) ((f4*)s_h)[tid - 240] = f4{0.f, 0.f, 0.f, 0.f};
  __syncthreads();

  int r = tid >> 2, q = tid & 3;     // 64 rows x 4 threads
  if (r < CR_) {
    const f4* wr = (const f4*)(w1 + (size_t)r * C_);   // 110 f4 per row
    const f4* ss = (const f4*)s_s;
    f4 acc = {0.f, 0.f, 0.f, 0.f};
    #pragma unroll
    for (int j0 = 0; j0 < 28; ++j0) {
      int j = q + j0 * 4;
      if (j < C_ / 4) { f4 w = wr[j], x = ss[j]; acc += w * x; }
    }
    float a = acc[0] + acc[1] + acc[2] + acc[3];
    a += __shfl_xor(a, 1, 64);
    a += __shfl_xor(a, 2, 64);
    if (q == 0) s_h[r] = fmaxf(a + b1[r], 0.f);
  }
  __syncthreads();

  for (int c = tid; c < C_; c += 256) {
    const f4* wc = (const f4*)(w2 + (size_t)c * CR_);  // 13 f4 per row
    const f4* hh = (const f4*)s_h;
    f4 acc = {0.f, 0.f, 0.f, 0.f};
    #pragma unroll
    for (int j = 0; j < 13; ++j) acc += wc[j] * hh[j];
    float a = acc[0] + acc[1] + acc[2] + acc[3] + b2[c];
    gate[b * C_ + c] = 1.f / (1.f + __expf(-a));
  }
}

// ------- K2: gating + bf16 + transpose, one block per (c-chunk, b) -------
__global__ __launch_bounds__(256) void k_scatter(
    const float* __restrict__ x177, const float* __restrict__ gate,
    unsigned short* __restrict__ gbf) {
  __shared__ __align__(16) unsigned short s_t[HW_ * TSS_];  // [49][72] bf16
  __shared__ float s_g[CCH_];
  int cc = blockIdx.x, b = blockIdx.y, tid = threadIdx.x;
  int c0 = cc * CCH_;
  int valid_c = (c0 + CCH_ <= C_) ? CCH_ : (C_ - c0);   // 64 or 56

  unsigned* zt = (unsigned*)s_t;
  for (int i = tid; i < HW_ * TSS_ / 2; i += 256) zt[i] = 0u;
  if (tid < CCH_) {
    int c = c0 + tid;
    s_g[tid] = (c < C_) ? gate[b * C_ + c] : 0.f;
  }
  __syncthreads();

  const f4* xp = (const f4*)(x177 + (size_t)b * (C_ * HW_) + (size_t)c0 * HW_);
  int nvec = valid_c * HW_ / 4;   // 784 or 686
  for (int it = 0; it < 4; ++it) {
    int idx = it * 256 + tid;
    if (idx < nvec) {
      f4 v = xp[idx];
      int e = idx * 4;
      #pragma unroll
      for (int j = 0; j < 4; ++j) {
        int ej = e + j;
        int cl = ej / HW_, hw = ej - cl * HW_;
        s_t[hw * TSS_ + cl] = f2bf(v[j] * s_g[cl]);
      }
    }
  }
  __syncthreads();

  unsigned short* gp = gbf + (size_t)b * HW_ * KP_ + c0;
  for (int it = 0; it < 2; ++it) {
    int p = it * 256 + tid;
    if (p < HW_ * (CCH_ / 8)) {
      int hw = p >> 3, cg = p & 7;
      *(bf8*)(gp + hw * KP_ + cg * 8) = *(const bf8*)(s_t + hw * TSS_ + cg * 8);
    }
  }
}

// ---- K3 (r15-best): 128o x 64m, BK=32, 24KB 2-slot dbuf, 6 blocks/CU ----
__global__ __launch_bounds__(256, 6) void k_gemm(const unsigned short* __restrict__ w3bf,
                                                 const unsigned short* __restrict__ gbf,
                                                 unsigned short* __restrict__ ybf,
                                                 float* __restrict__ gstats) {
  // buf: [A 128x32 (8KB) | B 64x32 (4KB)] = 12 KB; x2 dbuf = 24 KB
  __shared__ __align__(16) unsigned short lds[2 * 6144];
  int tid = threadIdx.x, lane = tid & 63, wv = tid >> 6;
  // XCD swizzle: 1568 = 8 XCD-chunks x (49 m-tiles x 4 o-tiles)
  int bid0 = blockIdx.x;
  int x = bid0 & 7, w = bid0 >> 3;          // w in [0,196)
  int ot = w & 3, mt = x * 49 + (w >> 2);
  int o0 = ot * 128, m0 = mt * 64;
  int wr = wv >> 1, wc = wv & 1;            // wave: 64o x 32m quadrant
  f4 acc[4][2] = {};
  const char* Ab = (const char*)w3bf;  // row stride 896 B
  const char* Bb = (const char*)gbf;   // row stride 896 B

  // staging unit: 16 rows x 4 chunks(16B); src chunk pre-XOR'd by row&3
  int rowl = lane >> 2;                     // 0..15
  int crg  = (lane & 3) ^ (rowl & 3);       // both-sides swizzle key
  auto stage = [&](int buf, int kt) {
    char* lb = (char*)lds + buf * 12288;
    int k0b = kt * 64;
    #pragma unroll
    for (int t = 0; t < 2; ++t) {           // A: 8 units, 128 rows
      int u = wv * 2 + t;
      int row = u * 16 + rowl;
      gld16(Ab + (size_t)(o0 + row) * 896 + k0b + crg * 16, lb + u * 1024);
    }
    {                                       // B: 4 units, 64 rows
      int u = wv;
      int row = u * 16 + rowl;
      gld16(Bb + (size_t)(m0 + row) * 896 + k0b + crg * 16, lb + 8192 + u * 1024);
    }
  };

  stage(0, 0);
  asm volatile("s_waitcnt vmcnt(0)" ::: "memory");
  __builtin_amdgcn_s_barrier();

  int rl = lane & 15, l16q = lane >> 4;
  int ch = (l16q ^ (rl & 3)) * 16;          // swizzled read chunk (bytes)
  for (int kt = 0; kt < NKT_; ++kt) {
    int cur = kt & 1;
    if (kt + 1 < NKT_) stage(cur ^ 1, kt + 1);   // prefetch under compute

    const char* base = (const char*)lds + cur * 12288;
    bf8 a[4], bb[2];
    #pragma unroll
    for (int i = 0; i < 4; ++i)
      a[i] = *(const bf8*)(base + (wr * 64 + i * 16 + rl) * 64 + ch);
    #pragma unroll
    for (int j = 0; j < 2; ++j)
      bb[j] = *(const bf8*)(base + 8192 + (wc * 32 + j * 16 + rl) * 64 + ch);
    // retire LDS reads BEFORE the barrier (rule-#18 WAR fence)
    asm volatile("s_waitcnt lgkmcnt(0)" ::: "memory");
    __builtin_amdgcn_sched_barrier(0);

    #pragma unroll
    for (int i = 0; i < 4; ++i)
      #pragma unroll
      for (int j = 0; j < 2; ++j)
        acc[i][j] = __builtin_amdgcn_mfma_f32_16x16x32_bf16(a[i], bb[j], acc[i][j], 0, 0, 0);

    if (kt + 1 < NKT_) {
      asm volatile("s_waitcnt vmcnt(0)" ::: "memory");
      __builtin_amdgcn_s_barrier();
    }
  }

  // D layout: col = lane&15 (m), row = (lane>>4)*4 + reg (o); store bf16
  int col = rl, r4 = l16q * 4;
  #pragma unroll
  for (int i = 0; i < 4; ++i) {
    int ob = o0 + wr * 64 + i * 16 + r4;
    #pragma unroll
    for (int j = 0; j < 2; ++j) {
      int m = m0 + wc * 32 + j * 16 + col;
      #pragma unroll
      for (int r = 0; r < 4; ++r) {
        int o = ob + r;
        if (o < C_) ybf[(size_t)o * M_ + m] = f2bf(acc[i][j][r]);
      }
    }
  }

  // fused stats: per-block sum/sumsq over this block's 64 m-cols
  __syncthreads();
  float* part = (float*)lds;            // [128 rows][2 wc][2 {sum,sq}]
  #pragma unroll
  for (int i = 0; i < 4; ++i) {
    float s[4], q[4];
    #pragma unroll
    for (int r = 0; r < 4; ++r) {
      float ss = 0.f, qq = 0.f;
      #pragma unroll
      for (int j = 0; j < 2; ++j) { float v = acc[i][j][r]; ss += v; qq += v * v; }
      s[r] = ss; q[r] = qq;
    }
    #pragma unroll
    for (int off = 1; off < 16; off <<= 1) {
      #pragma unroll
      for (int r = 0; r < 4; ++r) {
        s[r] += __shfl_xor(s[r], off, 64);
        q[r] += __shfl_xor(q[r], off, 64);
      }
    }
    if (rl == 0) {
      int row = wr * 64 + i * 16 + r4;
      #pragma unroll
      for (int r = 0; r < 4; ++r) {
        part[(row + r) * 4 + wc * 2 + 0] = s[r];
        part[(row + r) * 4 + wc * 2 + 1] = q[r];
      }
    }
  }
  __syncthreads();
  {
    int row = tid >> 1, which = tid & 1;
    float v = part[row * 4 + which] + part[row * 4 + 2 + which];
    int o = o0 + row;
    if (o < C_) atomicAdd(&gstats[o * 2 + which], v);
  }
}

// -------- K4: block-per-b normalize, flat f4 stores (fully coalesced) --------
__global__ __launch_bounds__(256) void k_norm(const unsigned short* __restrict__ ybf,
                                              const float* __restrict__ gstats,
                                              const float* __restrict__ gamma,
                                              const float* __restrict__ beta,
                                              float* __restrict__ out) {
  __shared__ float s_sc[C_], s_sh[C_];
  int b = blockIdx.x, seg = blockIdx.y, tid = threadIdx.x;
  for (int o = tid; o < C_; o += 256) {
    float S = gstats[o * 2 + 0], Q = gstats[o * 2 + 1];
    float mean = S * (1.f / (float)M_);
    float var  = Q * (1.f / (float)M_) - mean * mean;
    float sc = gamma[o] * rsqrtf(var + 1e-5f);
    s_sc[o] = sc;
    s_sh[o] = beta[o] - mean * sc;
  }
  __syncthreads();
  // out region for b: 21560 floats = 5390 f4 (16B-aligned); split in 2 segs
  f4* ob = (f4*)(out + (size_t)b * (C_ * HW_));
  int mb = b * HW_;
  for (int u = seg * 2695 + tid; u < (seg + 1) * 2695; u += 256) {
    int f = u * 4;
    f4 v;
    #pragma unroll
    for (int j = 0; j < 4; ++j) {
      int fj = f + j;
      int o = fj / HW_, hw = fj - o * HW_;
      v[j] = bf2f(ybf[(size_t)o * M_ + mb + hw]) * s_sc[o] + s_sh[o];
    }
    ob[u] = v;
  }
}

extern "C" void kernel_launch(void* const* d_in, const int* in_sizes, int n_in,
                              void* d_out, int out_size, void* d_ws, size_t ws_size,
                              hipStream_t stream) {
  const float* x178 = (const float*)d_in[0];
  const float* x177 = (const float*)d_in[1];
  const float* w1   = (const float*)d_in[2];
  const float* b1   = (const float*)d_in[3];
  const float* w2   = (const float*)d_in[4];
  const float* b2   = (const float*)d_in[5];
  const float* w3   = (const float*)d_in[6];
  const float* gamma= (const float*)d_in[7];
  const float* beta = (const float*)d_in[8];
  float* out = (float*)d_out;

  char* ws = (char*)d_ws;
  unsigned short* w3bf = (unsigned short*)ws;                        // 512*448*2
  unsigned short* gbf  = (unsigned short*)(ws + 458752);             // 25088*448*2
  unsigned short* ybf  = (unsigned short*)(ws + 458752 + 22478848);  // region reserves 44MB
  float* gstats        = (float*)(ws + 458752 + 22478848 + 44154880);
  float* gate          = (float*)ybf;  // consumed by k_scatter before k_gemm writes ybf

  hipLaunchKernelGGL(k_prep_gate, dim3(896 + B_), dim3(256), 0, stream,
                     w3, w3bf, gstats, x178, w1, b1, w2, b2, gate);
  hipLaunchKernelGGL(k_scatter, dim3(KP_ / CCH_, B_), dim3(256), 0, stream,
                     x177, gate, gbf);
  hipLaunchKernelGGL(k_gemm, dim3((M_ / 64) * (OP_ / 128)), dim3(256), 0, stream,
                     w3bf, gbf, ybf, gstats);
  hipLaunchKernelGGL(k_norm, dim3(B_, 2), dim3(256), 0, stream,
                     ybf, gstats, gamma, beta, out);
}